// Round 18
// baseline (227.006 us; speedup 1.0000x reference)
//
#include <hip/hip_runtime.h>
#include <hip/hip_bf16.h>
#include <cstdint>
#include <cstddef>

// Problem constants (fixed by reference)
#define BB 4
#define NN 4096
#define NROW (BB*NN)          // 16384 rows
#define CAP3 512              // max survivors handled by k3 (8 sort rounds)
#define ZSTAR 2.17f           // row-adaptive screen: T = 64 - z*sqrt(128+4*xx)
#define SLACK 0.40            // guard slack: > E = 0.31 (fp16 screen + xx-in-K)

typedef float v2f   __attribute__((ext_vector_type(2)));
typedef float f32x16 __attribute__((ext_vector_type(16)));
typedef short s16x8 __attribute__((ext_vector_type(8)));
typedef _Float16 f16x8 __attribute__((ext_vector_type(8)));

__device__ __forceinline__ v2f pkfma(v2f a, v2f b, v2f c) {
  return __builtin_elementwise_fma(a, b, c);
}

// 64-lane bitonic sort (ascending), full network
__device__ __forceinline__ unsigned long long sort64(unsigned long long S, int lane) {
  #pragma unroll
  for (int kk = 2; kk <= 64; kk <<= 1) {
    #pragma unroll
    for (int j = kk >> 1; j > 0; j >>= 1) {
      unsigned long long o = __shfl_xor(S, j);
      bool up    = ((lane & kk) == 0);
      bool lower = ((lane & j) == 0);
      unsigned long long mn = (S < o) ? S : o;
      unsigned long long mx = (S < o) ? o : S;
      S = (lower == up) ? mn : mx;
    }
  }
  return S;
}
// given L sorted asc and S sorted asc (across lanes), return lowest 64 sorted asc
__device__ __forceinline__ unsigned long long merge_low64(
    unsigned long long L, unsigned long long S, int lane) {
  unsigned long long Sr = __shfl(S, 63 - lane);
  unsigned long long lo = (L < Sr) ? L : Sr;
  #pragma unroll
  for (int j = 32; j > 0; j >>= 1) {
    unsigned long long o = __shfl_xor(lo, j);
    unsigned long long mn = (lo < o) ? lo : o;
    unsigned long long mx = (lo < o) ? o : lo;
    lo = ((lane & j) == 0) ? mn : mx;
  }
  return lo;
}

// ---------------------------------------------------------------------------
// K1: prep. xT f32 [point][c]; xh2 fp16 [point][80] (64 dims + xx at 64 + 0s);
// xxd f64 norms; Trow; uT = W1.x, vT = (W2-W1).x
// ---------------------------------------------------------------------------
__global__ __launch_bounds__(256) void k1_prep(
    const float* __restrict__ x, const float* __restrict__ W,
    float* __restrict__ xT, unsigned short* __restrict__ xh2,
    double* __restrict__ xxd, float* __restrict__ Trow,
    float* __restrict__ uT, float* __restrict__ vT)
{
  __shared__ float xc[64][65];   // [c][n]
  __shared__ float xr[64][68];   // [n][c]
  __shared__ float w1[64][65];
  __shared__ float wd[64][65];
  int t = threadIdx.x;
  int b  = blockIdx.x >> 6;
  int n0 = (blockIdx.x & 63) * 64;

  for (int i = t; i < 4096; i += 256) {
    int o = i >> 6, c = i & 63;
    float a = W[o*128 + c];
    w1[o][c] = a;
    wd[o][c] = W[o*128 + 64 + c] - a;
  }
  for (int i = t; i < 4096; i += 256) {
    int c = i >> 6, n = i & 63;
    xc[c][n] = x[((size_t)b*64 + c)*4096 + n0 + n];
  }
  __syncthreads();

  for (int i = t; i < 4096; i += 256) {
    int n = i >> 6, c = i & 63;
    float v = xc[c][n];
    xr[n][c] = v;
    size_t pt = (size_t)b*4096 + n0 + n;
    xT[pt*64 + c] = v;
    xh2[pt*80 + c] = __builtin_bit_cast(unsigned short, (_Float16)v);  // RNE
  }
  if (t < 64) {
    int n = t;
    float s0=0,s1=0,s2=0,s3=0; double sd=0.0;
    for (int c = 0; c < 64; c += 4) {
      float a0=xc[c][n],a1=xc[c+1][n],a2=xc[c+2][n],a3=xc[c+3][n];
      s0=fmaf(a0,a0,s0); s1=fmaf(a1,a1,s1); s2=fmaf(a2,a2,s2); s3=fmaf(a3,a3,s3);
      sd += (double)a0*a0 + (double)a1*a1 + (double)a2*a2 + (double)a3*a3;
    }
    float xxv = (s0+s1)+(s2+s3);
    size_t ri = (size_t)b*4096 + n0 + n;
    xxd[ri] = sd;
    Trow[ri] = fmaf(-ZSTAR, sqrtf(fmaf(4.0f, xxv, 128.0f)), 64.0f);
    size_t xb2 = ri*80 + 64;
    xh2[xb2] = __builtin_bit_cast(unsigned short, (_Float16)xxv);
    #pragma unroll
    for (int q = 1; q < 16; ++q) xh2[xb2 + q] = 0;
  }
  v2f w1r[32], wdr[32];
  int o = t & 63;
  #pragma unroll
  for (int j = 0; j < 32; ++j) {
    w1r[j].x = w1[o][2*j]; w1r[j].y = w1[o][2*j+1];
    wdr[j].x = wd[o][2*j]; wdr[j].y = wd[o][2*j+1];
  }
  __syncthreads();

  for (int i = t; i < 4096; i += 256) {
    int n = i >> 6;
    v2f au; au.x=0.f; au.y=0.f;
    v2f av; av.x=0.f; av.y=0.f;
    #pragma unroll
    for (int cb = 0; cb < 16; ++cb) {
      float4 xv = *(const float4*)&xr[n][cb*4];
      v2f p0; p0.x = xv.x; p0.y = xv.y;
      v2f p1; p1.x = xv.z; p1.y = xv.w;
      au = pkfma(w1r[2*cb],   p0, au);
      au = pkfma(w1r[2*cb+1], p1, au);
      av = pkfma(wdr[2*cb],   p0, av);
      av = pkfma(wdr[2*cb+1], p1, av);
    }
    size_t idx = ((size_t)b*4096 + n0 + n)*64 + o;
    uT[idx] = au.x + au.y;
    vT[idx] = av.x + av.y;
  }
}

// ---------------------------------------------------------------------------
// K2: fp16 MFMA Gram screen -> survivor BITMAP. Inverted orientation:
// A = m-points (rows), B = n-points (cols, lane-owned). Screen value baked
// into K-dim 64 (A: xx_m, B: -0.5) so compare is S' > -T_n/2 (per-lane reg).
// ---------------------------------------------------------------------------
__global__ __launch_bounds__(256) void k2_screen(
    const unsigned short* __restrict__ xh2, const float* __restrict__ Trow,
    unsigned* __restrict__ bitmap)
{
  int t  = threadIdx.x;
  int nblk = blockIdx.x >> 3;
  int ms   = blockIdx.x & 7;
  int row0 = nblk * 128;
  int b = row0 >> 12;
  int wv = t >> 6, lane = t & 63;
  int lr = lane & 31, oct = lane >> 5;
  int n = row0 + wv*32 + lr;             // lane-owned output row

  s16x8 bn[5];
  #pragma unroll
  for (int ks = 0; ks < 4; ++ks)
    bn[ks] = *(const s16x8*)(xh2 + (size_t)n*80 + ks*16 + oct*8);
  {
    s16x8 z;
    #pragma unroll
    for (int q = 0; q < 8; ++q) z[q] = 0;
    if (!oct) z[0] = (short)0xB800;      // -0.5 in fp16
    bn[4] = z;
  }
  float cn = -0.5f * Trow[n];

  const unsigned short* xmB = xh2 + (size_t)b*4096*80;
  int mbase = ms * 512;

  for (int mt = 0; mt < 8; ++mt) {
    int m0 = mbase + mt*64;
    s16x8 am0[5], am1[5];
    #pragma unroll
    for (int ks = 0; ks < 4; ++ks) {
      am0[ks] = *(const s16x8*)(xmB + (size_t)(m0 + lr)*80      + ks*16 + oct*8);
      am1[ks] = *(const s16x8*)(xmB + (size_t)(m0 + 32 + lr)*80 + ks*16 + oct*8);
    }
    am0[4] = *(const s16x8*)(xmB + (size_t)(m0 + lr)*80      + 64 + oct*8);
    am1[4] = *(const s16x8*)(xmB + (size_t)(m0 + 32 + lr)*80 + 64 + oct*8);

    f32x16 a0, a1;
    #pragma unroll
    for (int i = 0; i < 16; ++i) { a0[i] = 0.f; a1[i] = 0.f; }
    #pragma unroll
    for (int ks = 0; ks < 5; ++ks) {
      f16x8 B = __builtin_bit_cast(f16x8, bn[ks]);
      a0 = __builtin_amdgcn_mfma_f32_32x32x16_f16(
             __builtin_bit_cast(f16x8, am0[ks]), B, a0, 0, 0, 0);
      a1 = __builtin_amdgcn_mfma_f32_32x32x16_f16(
             __builtin_bit_cast(f16x8, am1[ks]), B, a1, 0, 0, 0);
    }

    unsigned ua[4] = {0u,0u,0u,0u}, ub[4] = {0u,0u,0u,0u};
    #pragma unroll
    for (int i = 0; i < 16; ++i) {
      int p = (i & 3) + 8*(i >> 2) + 4*oct;   // C/D row map (measured)
      unsigned bit = 1u << p;
      ua[i & 3] = (a0[i] > cn) ? (ua[i & 3] | bit) : ua[i & 3];
      ub[i & 3] = (a1[i] > cn) ? (ub[i & 3] | bit) : ub[i & 3];
    }
    unsigned u0 = (ua[0] | ua[1]) | (ua[2] | ua[3]);
    unsigned u1 = (ub[0] | ub[1]) | (ub[2] | ub[3]);
    unsigned w0 = u0 | (unsigned)__shfl_xor((int)u0, 32);
    unsigned w1 = u1 | (unsigned)__shfl_xor((int)u1, 32);
    bitmap[(size_t)n*128 + ms*16 + mt*2 + oct] = oct ? w1 : w0;
  }
}

// ---------------------------------------------------------------------------
// K3: per-row wave. Bitmap -> compact (<=512); <=8 rounds f64 rescore +
// sort64 + merge_low64; guard d20-xxn < Trow-SLACK proves exactness;
// gather/max epilogue.
// ---------------------------------------------------------------------------
__global__ __launch_bounds__(256) void k3_select(
    const float* __restrict__ xT, const double* __restrict__ xxd,
    const float* __restrict__ Trow, const unsigned* __restrict__ bitmap,
    const float* __restrict__ uT, const float* __restrict__ vT,
    float* __restrict__ stage, double* __restrict__ pS1, double* __restrict__ pS2,
    unsigned* __restrict__ slowcnt, unsigned* __restrict__ slowlist)
{
  __shared__ unsigned short candm[4][CAP3];
  int wv = threadIdx.x >> 6, lane = threadIdx.x & 63;
  int row = blockIdx.x * 4 + wv;
  int b = row >> 12;

  double s1t = 0.0, s2t = 0.0;
  double xxn = xxd[row];

  uint2 wds = *(const uint2*)&bitmap[(size_t)row*128 + lane*2];
  int myc = __popc(wds.x) + __popc(wds.y);
  int inc = myc;
  #pragma unroll
  for (int d = 1; d < 64; d <<= 1) {
    int v = __shfl_up(inc, d);
    if (lane >= d) inc += v;
  }
  int total = __shfl(inc, 63);
  int off = inc - myc;
  bool slow = (total < 20) || (total > CAP3);

  if (!slow) {
    unsigned w = wds.x; int mb = lane*64;
    while (w) { int j = __ffs(w) - 1; w &= w - 1;
                candm[wv][off++] = (unsigned short)(mb + j); }
    w = wds.y; mb = lane*64 + 32;
    while (w) { int j = __ffs(w) - 1; w &= w - 1;
                candm[wv][off++] = (unsigned short)(mb + j); }
  }
  __builtin_amdgcn_wave_barrier();

  if (!slow) {
    const float* pn = xT + (size_t)row*64;
    int nr = (total + 63) >> 6;
    unsigned long long L = ~0ull;
    for (int r = 0; r < nr; ++r) {
      int ci = r*64 + lane;
      unsigned long long S = ~0ull;
      if (ci < total) {
        int m = (int)candm[wv][ci];
        const float* pm = xT + ((size_t)b*4096 + m)*64;
        double acc0 = 0.0, acc1 = 0.0;
        #pragma unroll
        for (int c5 = 0; c5 < 64; c5 += 4) {
          float4 A = *(const float4*)(pn + c5);
          float4 B = *(const float4*)(pm + c5);
          acc0 = fma((double)A.x, (double)B.x, acc0);
          acc1 = fma((double)A.y, (double)B.y, acc1);
          acc0 = fma((double)A.z, (double)B.z, acc0);
          acc1 = fma((double)A.w, (double)B.w, acc1);
        }
        double d = xxn + xxd[(size_t)b*4096 + m] - 2.0*(acc0 + acc1);
        d = fmax(d, 0.0);
        S = (((unsigned long long)__double_as_longlong(d)) & ~0xFFFull)
          | (unsigned long long)m;            // tie -> lower index (lax.top_k)
      }
      S = sort64(S, lane);
      L = (r == 0) ? S : merge_low64(L, S, lane);
    }
    unsigned long long k19 = __shfl(L, 19);
    double d20 = __longlong_as_double((long long)(k19 & ~0xFFFull));
    float Tr = Trow[row];
    if (!(d20 - xxn < (double)Tr - SLACK)) {
      slow = true;
    } else {
      int mlow = (int)(L & 0xFFFull);          // lanes 0..19 = top-20
      const float* ub = uT + (size_t)b*4096*64;
      float mx = -3.4e38f, s1 = 0.f, s2 = 0.f;
      #pragma unroll
      for (int k = 0; k < 20; ++k) {
        int m = __shfl(mlow, k);
        float g = ub[(size_t)m*64 + lane];
        mx = fmaxf(mx, g); s1 += g; s2 = fmaf(g, g, s2);
      }
      size_t ro = (size_t)row*64 + lane;
      float v = vT[ro];
      stage[ro] = mx + v;
      double dv = (double)v;
      s1t = (double)s1 + 20.0*dv;
      s2t = (double)s2 + 2.0*dv*(double)s1 + 20.0*dv*dv;
    }
  }
  if (slow && lane == 0) {
    unsigned i = atomicAdd(slowcnt, 1u); slowlist[i] = row;
  }
  pS1[(size_t)row*64 + lane] = s1t;   // zeros for slow rows (k3b adds theirs)
  pS2[(size_t)row*64 + lane] = s2t;
}

// ---------------------------------------------------------------------------
// K3b: slow path (~320 rows). COALESCED scan: per round of 64 rows, 16-lane
// groups own one row each; lane q loads col-quad q of the row (wave load =
// 4 consecutive rows = 1KB contiguous, 16 segments vs 64). Exact f64 dot via
// 4-step shfl_xor tree; sums parked in LDS keybuf; keys assembled per-lane
// with coalesced xxd loads. Sort-on-demand (r17-validated) on top.
// ---------------------------------------------------------------------------
__global__ __launch_bounds__(256) void k3b_slow(
    const float* __restrict__ xT, const double* __restrict__ xxd,
    const unsigned* __restrict__ slowcnt, const unsigned* __restrict__ slowlist,
    const float* __restrict__ uT, const float* __restrict__ vT,
    float* __restrict__ stage, double* __restrict__ k3bS1, double* __restrict__ k3bS2)
{
  __shared__ unsigned long long wtop[4][64];
  __shared__ unsigned long long pend[4][64];
  __shared__ double keybuf[4][64];
  __shared__ unsigned t20[20];
  unsigned nslow = *slowcnt;
  int t = threadIdx.x, wv = t >> 6, lane = t & 63;
  int g = lane >> 4, q = lane & 15;
  for (unsigned ii = blockIdx.x; ii < nslow; ii += gridDim.x) {
    int row = (int)slowlist[ii];
    int b = row >> 12, n = row & 4095;
    const float* xb = xT + (size_t)b*4096*64;
    const double* xxb = xxd + (size_t)b*4096;
    double xxn = xxb[n];
    // resident quad of pn for this lane's column slice
    float4 Aq = *(const float4*)(xb + (size_t)n*64 + q*4);

    unsigned long long L;
    unsigned long long kth;
    int pc = 0;
    for (int r = 0; r < 16; ++r) {
      int mbase = wv*1024 + r*64;
      // 16 its: group g computes dot of row mbase+it*4+g
      #pragma unroll
      for (int it = 0; it < 16; ++it) {
        int mr = mbase + it*4 + g;
        float4 Bq = *(const float4*)(xb + (size_t)mr*64 + q*4);
        double p = fma((double)Aq.x, (double)Bq.x,
                   fma((double)Aq.y, (double)Bq.y,
                   fma((double)Aq.z, (double)Bq.z,
                       (double)Aq.w * (double)Bq.w)));
        p += __shfl_xor(p, 1);
        p += __shfl_xor(p, 2);
        p += __shfl_xor(p, 4);
        p += __shfl_xor(p, 8);
        if (q == 0) keybuf[wv][it*4 + g] = p;
      }
      __builtin_amdgcn_wave_barrier();
      int m = mbase + lane;
      double d = xxn + xxb[m] - 2.0 * keybuf[wv][lane];
      d = fmax(d, 0.0);
      unsigned long long S =
          (((unsigned long long)__double_as_longlong(d)) & ~0xFFFull)
        | (unsigned long long)m;              // tie -> lower index
      __builtin_amdgcn_wave_barrier();
      if (r == 0) {
        L = sort64(S, lane);
        kth = __shfl(L, 63);
        continue;
      }
      bool take = (S < kth);
      unsigned long long mk = __ballot(take);
      int cnt = __popcll(mk);
      if (pc + cnt > 64) {                    // flush pending
        __builtin_amdgcn_wave_barrier();
        unsigned long long P = (lane < pc) ? pend[wv][lane] : ~0ull;
        P = sort64(P, lane);
        L = merge_low64(L, P, lane);
        kth = __shfl(L, 63);
        pc = 0;
      }
      if (take) {
        int pos = pc + __popcll(mk & ((1ull << lane) - 1ull));
        pend[wv][pos] = S;
      }
      pc += cnt;
      __builtin_amdgcn_wave_barrier();
    }
    if (pc > 0) {                             // final flush
      __builtin_amdgcn_wave_barrier();
      unsigned long long P = (lane < pc) ? pend[wv][lane] : ~0ull;
      P = sort64(P, lane);
      L = merge_low64(L, P, lane);
    }
    wtop[wv][lane] = L;
    __syncthreads();
    if (wv == 0) {
      unsigned long long m01 = merge_low64(wtop[0][lane],
                                           wtop[1][lane], lane);
      unsigned long long m23 = merge_low64(wtop[2][lane],
                                           wtop[3][lane], lane);
      unsigned long long F = merge_low64(m01, m23, lane);
      if (lane < 20) t20[lane] = (unsigned)(F & 0xFFFull);
    }
    __syncthreads();
    if (t < 64) {
      const float* ub = uT + (size_t)b*4096*64;
      float mx = -3.4e38f, s1 = 0.f, s2 = 0.f;
      #pragma unroll
      for (int k = 0; k < 20; ++k) {
        unsigned m = t20[k];
        float gg = ub[(size_t)m*64 + t];
        mx = fmaxf(mx, gg); s1 += gg; s2 = fmaf(gg, gg, s2);
      }
      size_t ro = ((size_t)b*4096 + n)*64 + t;
      float v = vT[ro];
      stage[ro] = mx + v;
      double dv = (double)v;
      __hip_atomic_fetch_add(&k3bS1[b*64 + t], (double)s1 + 20.0*dv,
                             __ATOMIC_RELAXED, __HIP_MEMORY_SCOPE_AGENT);
      __hip_atomic_fetch_add(&k3bS2[b*64 + t], (double)s2 + 2.0*dv*(double)s1 + 20.0*dv*dv,
                             __ATOMIC_RELAXED, __HIP_MEMORY_SCOPE_AGENT);
    }
    __syncthreads();
  }
}

// ---------------------------------------------------------------------------
// K4a1: stage-1 reduction. 256 blocks; block reduces 64 rows -> part[blk][o].
// ---------------------------------------------------------------------------
__global__ __launch_bounds__(256) void k4a1_reduce(
    const double* __restrict__ pS1, const double* __restrict__ pS2,
    double* __restrict__ part1, double* __restrict__ part2)
{
  __shared__ double r1[4][64], r2[4][64];
  int blk = blockIdx.x;                 // rows blk*64 .. blk*64+63
  int t = threadIdx.x, wv = t >> 6, o = t & 63;
  size_t rbase = (size_t)blk*64 + wv*16;
  double s1 = 0.0, s2 = 0.0;
  for (int j = 0; j < 16; ++j) {
    s1 += pS1[(rbase + j)*64 + o];
    s2 += pS2[(rbase + j)*64 + o];
  }
  r1[wv][o] = s1; r2[wv][o] = s2;
  __syncthreads();
  if (wv == 0) {
    part1[(size_t)blk*64 + o] = r1[0][o]+r1[1][o]+r1[2][o]+r1[3][o];
    part2[(size_t)blk*64 + o] = r2[0][o]+r2[1][o]+r2[2][o]+r2[3][o];
  }
}

// ---------------------------------------------------------------------------
// K4a2: stage-2. 4 blocks; reduce 64 chunk-partials per (b,o) + k3b -> params.
// ---------------------------------------------------------------------------
__global__ __launch_bounds__(256) void k4a2_params(
    const double* __restrict__ part1, const double* __restrict__ part2,
    const double* __restrict__ k3bS1, const double* __restrict__ k3bS2,
    float2* __restrict__ params)
{
  __shared__ double r1[4][64], r2[4][64];
  int b = blockIdx.x;
  int t = threadIdx.x, wv = t >> 6, o = t & 63;
  double s1 = 0.0, s2 = 0.0;
  for (int j = wv*16; j < wv*16 + 16; ++j) {
    s1 += part1[((size_t)b*64 + j)*64 + o];
    s2 += part2[((size_t)b*64 + j)*64 + o];
  }
  r1[wv][o] = s1; r2[wv][o] = s2;
  __syncthreads();
  if (wv == 0) {
    double S1 = k3bS1[b*64 + o] + r1[0][o]+r1[1][o]+r1[2][o]+r1[3][o];
    double S2 = k3bS2[b*64 + o] + r2[0][o]+r2[1][o]+r2[2][o]+r2[3][o];
    double inv = 1.0 / (4096.0 * 20.0);
    double mean = S1 * inv;
    double var  = S2 * inv - mean * mean;
    float2 pr; pr.x = (float)mean; pr.y = (float)rsqrt(var + 1e-5);
    params[b*64 + o] = pr;
  }
}

// ---------------------------------------------------------------------------
// K4b: normalize + leaky-ReLU + transpose [point][o] -> [b][o][n] via LDS.
// ---------------------------------------------------------------------------
__global__ __launch_bounds__(256) void k4b_final(
    const float* __restrict__ stage, const float2* __restrict__ params,
    float* __restrict__ out)
{
  __shared__ float tile[64][65];
  int blk = blockIdx.x;
  int b = blk >> 6, n0 = (blk & 63) * 64;
  int t = threadIdx.x;
  int o = t & 63;
  float2 pr = params[b*64 + o];
  for (int i = t; i < 4096; i += 256) {
    int nn = i >> 6;
    float y = (stage[((size_t)b*4096 + n0 + nn)*64 + o] - pr.x) * pr.y;
    tile[nn][o] = (y >= 0.f) ? y : 0.2f * y;
  }
  __syncthreads();
  for (int i = t; i < 4096; i += 256) {
    int oo = i >> 6, nn = i & 63;
    out[((size_t)(b*64 + oo))*4096 + n0 + nn] = tile[nn][oo];
  }
}

// ---------------------------------------------------------------------------
extern "C" void kernel_launch(void* const* d_in, const int* in_sizes, int n_in,
                              void* d_out, int out_size, void* d_ws, size_t ws_size,
                              hipStream_t stream)
{
  (void)in_sizes; (void)n_in; (void)out_size; (void)ws_size;
  const float* x = (const float*)d_in[0];   // (4,64,4096)
  const float* W = (const float*)d_in[1];   // (64,128)
  float* out = (float*)d_out;

  char* ws = (char*)d_ws;
  size_t off = 0;
  auto alloc = [&](size_t bytes) {
    char* p = ws + off;
    off = (off + bytes + 255) & ~(size_t)255;
    return p;
  };
  float*          uT       = (float*)         alloc((size_t)NROW*64*4);
  float*          vT       = (float*)         alloc((size_t)NROW*64*4);
  float*          xT       = (float*)         alloc((size_t)NROW*64*4);
  float*          stage    = (float*)         alloc((size_t)NROW*64*4);
  unsigned short* xh2      = (unsigned short*)alloc((size_t)NROW*80*2);
  double*         xxd      = (double*)        alloc((size_t)NROW*8);
  float*          Trow     = (float*)         alloc((size_t)NROW*4);
  double*         pS1      = (double*)        alloc((size_t)NROW*64*8);
  double*         pS2      = (double*)        alloc((size_t)NROW*64*8);
  double*         part1    = (double*)        alloc((size_t)256*64*8);
  double*         part2    = (double*)        alloc((size_t)256*64*8);
  unsigned*       bitmap   = (unsigned*)      alloc((size_t)NROW*128*4);
  float2*         params   = (float2*)        alloc(256*8);
  // zeroed region (contiguous): slowcnt, k3bS1, k3bS2
  unsigned*       slowcnt  = (unsigned*)      alloc(256);
  double*         k3bS1    = (double*)        alloc(256*8);
  double*         k3bS2    = (double*)        alloc(256*8);
  unsigned*       slowlist = (unsigned*)      alloc((size_t)NROW*4);

  hipMemsetAsync(slowcnt, 0, 256 + 2048 + 2048, stream);

  k1_prep    <<<256,  256, 0, stream>>>(x, W, xT, xh2, xxd, Trow, uT, vT);
  k2_screen  <<<1024, 256, 0, stream>>>(xh2, Trow, bitmap);
  k3_select  <<<4096, 256, 0, stream>>>(xT, xxd, Trow, bitmap, uT, vT,
                                        stage, pS1, pS2, slowcnt, slowlist);
  k3b_slow   <<<512,  256, 0, stream>>>(xT, xxd, slowcnt, slowlist,
                                        uT, vT, stage, k3bS1, k3bS2);
  k4a1_reduce<<<256,  256, 0, stream>>>(pS1, pS2, part1, part2);
  k4a2_params<<<4,    256, 0, stream>>>(part1, part2, k3bS1, k3bS2, params);
  k4b_final  <<<256,  256, 0, stream>>>(stage, params, out);
}

// Round 19
// 223.499 us; speedup vs baseline: 1.0157x; 1.0157x over previous
//
#include <hip/hip_runtime.h>
#include <hip/hip_bf16.h>
#include <cstdint>
#include <cstddef>

// Problem constants (fixed by reference)
#define BB 4
#define NN 4096
#define NROW (BB*NN)          // 16384 rows
#define CAP3 512              // max survivors via screened path
#define ZSTAR 2.17f           // row-adaptive screen: T = 64 - z*sqrt(128+4*xx)
#define SLACK 0.40            // guard slack: > E = 0.31 (fp16 screen + xx-in-K)

typedef float v2f   __attribute__((ext_vector_type(2)));
typedef float f32x16 __attribute__((ext_vector_type(16)));
typedef short s16x8 __attribute__((ext_vector_type(8)));
typedef _Float16 f16x8 __attribute__((ext_vector_type(8)));

__device__ __forceinline__ v2f pkfma(v2f a, v2f b, v2f c) {
  return __builtin_elementwise_fma(a, b, c);
}

// 64-lane bitonic sort (ascending), full network
__device__ __forceinline__ unsigned long long sort64(unsigned long long S, int lane) {
  #pragma unroll
  for (int kk = 2; kk <= 64; kk <<= 1) {
    #pragma unroll
    for (int j = kk >> 1; j > 0; j >>= 1) {
      unsigned long long o = __shfl_xor(S, j);
      bool up    = ((lane & kk) == 0);
      bool lower = ((lane & j) == 0);
      unsigned long long mn = (S < o) ? S : o;
      unsigned long long mx = (S < o) ? o : S;
      S = (lower == up) ? mn : mx;
    }
  }
  return S;
}
// given L sorted asc and S sorted asc (across lanes), return lowest 64 sorted asc
__device__ __forceinline__ unsigned long long merge_low64(
    unsigned long long L, unsigned long long S, int lane) {
  unsigned long long Sr = __shfl(S, 63 - lane);
  unsigned long long lo = (L < Sr) ? L : Sr;
  #pragma unroll
  for (int j = 32; j > 0; j >>= 1) {
    unsigned long long o = __shfl_xor(lo, j);
    unsigned long long mn = (lo < o) ? lo : o;
    unsigned long long mx = (lo < o) ? o : lo;
    lo = ((lane & j) == 0) ? mn : mx;
  }
  return lo;
}

// ---------------------------------------------------------------------------
// K1: prep. xT f32 [point][c]; xh2 fp16 [point][80] (64 dims + xx at 64 + 0s);
// xxd f64 norms; Trow; uT = W1.x, vT = (W2-W1).x
// ---------------------------------------------------------------------------
__global__ __launch_bounds__(256) void k1_prep(
    const float* __restrict__ x, const float* __restrict__ W,
    float* __restrict__ xT, unsigned short* __restrict__ xh2,
    double* __restrict__ xxd, float* __restrict__ Trow,
    float* __restrict__ uT, float* __restrict__ vT)
{
  __shared__ float xc[64][65];   // [c][n]
  __shared__ float xr[64][68];   // [n][c]
  __shared__ float w1[64][65];
  __shared__ float wd[64][65];
  int t = threadIdx.x;
  int b  = blockIdx.x >> 6;
  int n0 = (blockIdx.x & 63) * 64;

  for (int i = t; i < 4096; i += 256) {
    int o = i >> 6, c = i & 63;
    float a = W[o*128 + c];
    w1[o][c] = a;
    wd[o][c] = W[o*128 + 64 + c] - a;
  }
  for (int i = t; i < 4096; i += 256) {
    int c = i >> 6, n = i & 63;
    xc[c][n] = x[((size_t)b*64 + c)*4096 + n0 + n];
  }
  __syncthreads();

  for (int i = t; i < 4096; i += 256) {
    int n = i >> 6, c = i & 63;
    float v = xc[c][n];
    xr[n][c] = v;
    size_t pt = (size_t)b*4096 + n0 + n;
    xT[pt*64 + c] = v;
    xh2[pt*80 + c] = __builtin_bit_cast(unsigned short, (_Float16)v);  // RNE
  }
  if (t < 64) {
    int n = t;
    float s0=0,s1=0,s2=0,s3=0; double sd=0.0;
    for (int c = 0; c < 64; c += 4) {
      float a0=xc[c][n],a1=xc[c+1][n],a2=xc[c+2][n],a3=xc[c+3][n];
      s0=fmaf(a0,a0,s0); s1=fmaf(a1,a1,s1); s2=fmaf(a2,a2,s2); s3=fmaf(a3,a3,s3);
      sd += (double)a0*a0 + (double)a1*a1 + (double)a2*a2 + (double)a3*a3;
    }
    float xxv = (s0+s1)+(s2+s3);
    size_t ri = (size_t)b*4096 + n0 + n;
    xxd[ri] = sd;
    Trow[ri] = fmaf(-ZSTAR, sqrtf(fmaf(4.0f, xxv, 128.0f)), 64.0f);
    size_t xb2 = ri*80 + 64;
    xh2[xb2] = __builtin_bit_cast(unsigned short, (_Float16)xxv);
    #pragma unroll
    for (int q = 1; q < 16; ++q) xh2[xb2 + q] = 0;
  }
  v2f w1r[32], wdr[32];
  int o = t & 63;
  #pragma unroll
  for (int j = 0; j < 32; ++j) {
    w1r[j].x = w1[o][2*j]; w1r[j].y = w1[o][2*j+1];
    wdr[j].x = wd[o][2*j]; wdr[j].y = wd[o][2*j+1];
  }
  __syncthreads();

  for (int i = t; i < 4096; i += 256) {
    int n = i >> 6;
    v2f au; au.x=0.f; au.y=0.f;
    v2f av; av.x=0.f; av.y=0.f;
    #pragma unroll
    for (int cb = 0; cb < 16; ++cb) {
      float4 xv = *(const float4*)&xr[n][cb*4];
      v2f p0; p0.x = xv.x; p0.y = xv.y;
      v2f p1; p1.x = xv.z; p1.y = xv.w;
      au = pkfma(w1r[2*cb],   p0, au);
      au = pkfma(w1r[2*cb+1], p1, au);
      av = pkfma(wdr[2*cb],   p0, av);
      av = pkfma(wdr[2*cb+1], p1, av);
    }
    size_t idx = ((size_t)b*4096 + n0 + n)*64 + o;
    uT[idx] = au.x + au.y;
    vT[idx] = av.x + av.y;
  }
}

// ---------------------------------------------------------------------------
// K2: fp16 MFMA Gram screen -> survivor BITMAP. Inverted orientation:
// A = m-points (rows), B = n-points (cols, lane-owned). Screen value baked
// into K-dim 64 (A: xx_m, B: -0.5) so compare is S' > -T_n/2 (per-lane reg).
// ---------------------------------------------------------------------------
__global__ __launch_bounds__(256) void k2_screen(
    const unsigned short* __restrict__ xh2, const float* __restrict__ Trow,
    unsigned* __restrict__ bitmap)
{
  int t  = threadIdx.x;
  int nblk = blockIdx.x >> 3;
  int ms   = blockIdx.x & 7;
  int row0 = nblk * 128;
  int b = row0 >> 12;
  int wv = t >> 6, lane = t & 63;
  int lr = lane & 31, oct = lane >> 5;
  int n = row0 + wv*32 + lr;             // lane-owned output row

  s16x8 bn[5];
  #pragma unroll
  for (int ks = 0; ks < 4; ++ks)
    bn[ks] = *(const s16x8*)(xh2 + (size_t)n*80 + ks*16 + oct*8);
  {
    s16x8 z;
    #pragma unroll
    for (int q = 0; q < 8; ++q) z[q] = 0;
    if (!oct) z[0] = (short)0xB800;      // -0.5 in fp16
    bn[4] = z;
  }
  float cn = -0.5f * Trow[n];

  const unsigned short* xmB = xh2 + (size_t)b*4096*80;
  int mbase = ms * 512;

  for (int mt = 0; mt < 8; ++mt) {
    int m0 = mbase + mt*64;
    s16x8 am0[5], am1[5];
    #pragma unroll
    for (int ks = 0; ks < 4; ++ks) {
      am0[ks] = *(const s16x8*)(xmB + (size_t)(m0 + lr)*80      + ks*16 + oct*8);
      am1[ks] = *(const s16x8*)(xmB + (size_t)(m0 + 32 + lr)*80 + ks*16 + oct*8);
    }
    am0[4] = *(const s16x8*)(xmB + (size_t)(m0 + lr)*80      + 64 + oct*8);
    am1[4] = *(const s16x8*)(xmB + (size_t)(m0 + 32 + lr)*80 + 64 + oct*8);

    f32x16 a0, a1;
    #pragma unroll
    for (int i = 0; i < 16; ++i) { a0[i] = 0.f; a1[i] = 0.f; }
    #pragma unroll
    for (int ks = 0; ks < 5; ++ks) {
      f16x8 B = __builtin_bit_cast(f16x8, bn[ks]);
      a0 = __builtin_amdgcn_mfma_f32_32x32x16_f16(
             __builtin_bit_cast(f16x8, am0[ks]), B, a0, 0, 0, 0);
      a1 = __builtin_amdgcn_mfma_f32_32x32x16_f16(
             __builtin_bit_cast(f16x8, am1[ks]), B, a1, 0, 0, 0);
    }

    unsigned ua[4] = {0u,0u,0u,0u}, ub[4] = {0u,0u,0u,0u};
    #pragma unroll
    for (int i = 0; i < 16; ++i) {
      int p = (i & 3) + 8*(i >> 2) + 4*oct;   // C/D row map (measured)
      unsigned bit = 1u << p;
      ua[i & 3] = (a0[i] > cn) ? (ua[i & 3] | bit) : ua[i & 3];
      ub[i & 3] = (a1[i] > cn) ? (ub[i & 3] | bit) : ub[i & 3];
    }
    unsigned u0 = (ua[0] | ua[1]) | (ua[2] | ua[3]);
    unsigned u1 = (ub[0] | ub[1]) | (ub[2] | ub[3]);
    unsigned w0 = u0 | (unsigned)__shfl_xor((int)u0, 32);
    unsigned w1 = u1 | (unsigned)__shfl_xor((int)u1, 32);
    bitmap[(size_t)n*128 + ms*16 + mt*2 + oct] = oct ? w1 : w0;
  }
}

// ---------------------------------------------------------------------------
// K3: per-row wave, SELF-CONTAINED (no slow-path kernel). Screened rows:
// bitmap -> compact (<=512) -> sort-on-demand rescore -> guard. Rows failing
// screen (total<20 / >CAP3) or guard RETRY with identity candidates (all
// 4096 m, 64 rounds) — exact by construction, throughput-hidden among
// 16384 co-resident waves. Wave-uniform 2-attempt loop.
// ---------------------------------------------------------------------------
__global__ __launch_bounds__(256) void k3_select(
    const float* __restrict__ xT, const double* __restrict__ xxd,
    const float* __restrict__ Trow, const unsigned* __restrict__ bitmap,
    const float* __restrict__ uT, const float* __restrict__ vT,
    float* __restrict__ stage, double* __restrict__ pS1, double* __restrict__ pS2)
{
  __shared__ unsigned short candm[4][CAP3];
  __shared__ unsigned long long pend[4][64];
  int wv = threadIdx.x >> 6, lane = threadIdx.x & 63;
  int row = blockIdx.x * 4 + wv;
  int b = row >> 12;

  double xxn = xxd[row];
  const double* xxb = xxd + (size_t)b*4096;

  uint2 wds = *(const uint2*)&bitmap[(size_t)row*128 + lane*2];
  int myc = __popc(wds.x) + __popc(wds.y);
  int inc = myc;
  #pragma unroll
  for (int d = 1; d < 64; d <<= 1) {
    int v = __shfl_up(inc, d);
    if (lane >= d) inc += v;
  }
  int total = __shfl(inc, 63);
  int off = inc - myc;
  bool fullscan = (total < 20) || (total > CAP3);

  if (!fullscan) {
    unsigned w = wds.x; int mb = lane*64;
    while (w) { int j = __ffs(w) - 1; w &= w - 1;
                candm[wv][off++] = (unsigned short)(mb + j); }
    w = wds.y; mb = lane*64 + 32;
    while (w) { int j = __ffs(w) - 1; w &= w - 1;
                candm[wv][off++] = (unsigned short)(mb + j); }
  }
  __builtin_amdgcn_wave_barrier();

  const float* pn = xT + (size_t)row*64;
  unsigned long long L = ~0ull;

  for (int attempt = 0; attempt < 2; ++attempt) {
    int ncand = fullscan ? 4096 : total;
    int nr = (ncand + 63) >> 6;
    unsigned long long kth = ~0ull;
    int pc = 0;
    L = ~0ull;
    for (int r = 0; r < nr; ++r) {
      int ci = r*64 + lane;
      unsigned long long S = ~0ull;
      if (ci < ncand) {
        int m = fullscan ? ci : (int)candm[wv][ci];
        const float* pm = xT + ((size_t)b*4096 + m)*64;
        double acc0 = 0.0, acc1 = 0.0;
        #pragma unroll
        for (int c5 = 0; c5 < 64; c5 += 4) {
          float4 A = *(const float4*)(pn + c5);
          float4 B = *(const float4*)(pm + c5);
          acc0 = fma((double)A.x, (double)B.x, acc0);
          acc1 = fma((double)A.y, (double)B.y, acc1);
          acc0 = fma((double)A.z, (double)B.z, acc0);
          acc1 = fma((double)A.w, (double)B.w, acc1);
        }
        double d = xxn + xxb[m] - 2.0*(acc0 + acc1);
        d = fmax(d, 0.0);
        S = (((unsigned long long)__double_as_longlong(d)) & ~0xFFFull)
          | (unsigned long long)m;            // tie -> lower index (lax.top_k)
      }
      if (r == 0) {
        L = sort64(S, lane);
        kth = __shfl(L, 63);
        continue;
      }
      bool take = (S < kth);
      unsigned long long mk = __ballot(take);
      int cnt = __popcll(mk);
      if (pc + cnt > 64) {                    // flush pending
        __builtin_amdgcn_wave_barrier();
        unsigned long long P = (lane < pc) ? pend[wv][lane] : ~0ull;
        P = sort64(P, lane);
        L = merge_low64(L, P, lane);
        kth = __shfl(L, 63);
        pc = 0;
      }
      if (take) {
        int pos = pc + __popcll(mk & ((1ull << lane) - 1ull));
        pend[wv][pos] = S;
      }
      pc += cnt;
      __builtin_amdgcn_wave_barrier();
    }
    if (pc > 0) {                             // final flush
      __builtin_amdgcn_wave_barrier();
      unsigned long long P = (lane < pc) ? pend[wv][lane] : ~0ull;
      P = sort64(P, lane);
      L = merge_low64(L, P, lane);
    }
    if (fullscan) break;                      // exact by construction
    // exactness guard for screened path
    unsigned long long k19 = __shfl(L, 19);
    double d20 = __longlong_as_double((long long)(k19 & ~0xFFFull));
    float Tr = Trow[row];
    if (d20 - xxn < (double)Tr - SLACK) break;
    fullscan = true;                          // rare: redo with all 4096
  }

  int mlow = (int)(L & 0xFFFull);             // lanes 0..19 = top-20
  const float* ub = uT + (size_t)b*4096*64;
  float mx = -3.4e38f, s1 = 0.f, s2 = 0.f;
  #pragma unroll
  for (int k = 0; k < 20; ++k) {
    int m = __shfl(mlow, k);
    float g = ub[(size_t)m*64 + lane];
    mx = fmaxf(mx, g); s1 += g; s2 = fmaf(g, g, s2);
  }
  size_t ro = (size_t)row*64 + lane;
  float v = vT[ro];
  stage[ro] = mx + v;
  double dv = (double)v;
  pS1[ro] = (double)s1 + 20.0*dv;
  pS2[ro] = (double)s2 + 2.0*dv*(double)s1 + 20.0*dv*dv;
}

// ---------------------------------------------------------------------------
// K4a1: stage-1 reduction. 256 blocks; block reduces 64 rows -> part[blk][o].
// ---------------------------------------------------------------------------
__global__ __launch_bounds__(256) void k4a1_reduce(
    const double* __restrict__ pS1, const double* __restrict__ pS2,
    double* __restrict__ part1, double* __restrict__ part2)
{
  __shared__ double r1[4][64], r2[4][64];
  int blk = blockIdx.x;                 // rows blk*64 .. blk*64+63
  int t = threadIdx.x, wv = t >> 6, o = t & 63;
  size_t rbase = (size_t)blk*64 + wv*16;
  double s1 = 0.0, s2 = 0.0;
  for (int j = 0; j < 16; ++j) {
    s1 += pS1[(rbase + j)*64 + o];
    s2 += pS2[(rbase + j)*64 + o];
  }
  r1[wv][o] = s1; r2[wv][o] = s2;
  __syncthreads();
  if (wv == 0) {
    part1[(size_t)blk*64 + o] = r1[0][o]+r1[1][o]+r1[2][o]+r1[3][o];
    part2[(size_t)blk*64 + o] = r2[0][o]+r2[1][o]+r2[2][o]+r2[3][o];
  }
}

// ---------------------------------------------------------------------------
// K4a2: stage-2. 4 blocks; reduce 64 chunk-partials per (b,o) -> params.
// ---------------------------------------------------------------------------
__global__ __launch_bounds__(256) void k4a2_params(
    const double* __restrict__ part1, const double* __restrict__ part2,
    float2* __restrict__ params)
{
  __shared__ double r1[4][64], r2[4][64];
  int b = blockIdx.x;
  int t = threadIdx.x, wv = t >> 6, o = t & 63;
  double s1 = 0.0, s2 = 0.0;
  for (int j = wv*16; j < wv*16 + 16; ++j) {
    s1 += part1[((size_t)b*64 + j)*64 + o];
    s2 += part2[((size_t)b*64 + j)*64 + o];
  }
  r1[wv][o] = s1; r2[wv][o] = s2;
  __syncthreads();
  if (wv == 0) {
    double S1 = r1[0][o]+r1[1][o]+r1[2][o]+r1[3][o];
    double S2 = r2[0][o]+r2[1][o]+r2[2][o]+r2[3][o];
    double inv = 1.0 / (4096.0 * 20.0);
    double mean = S1 * inv;
    double var  = S2 * inv - mean * mean;
    float2 pr; pr.x = (float)mean; pr.y = (float)rsqrt(var + 1e-5);
    params[b*64 + o] = pr;
  }
}

// ---------------------------------------------------------------------------
// K4b: normalize + leaky-ReLU + transpose [point][o] -> [b][o][n] via LDS.
// ---------------------------------------------------------------------------
__global__ __launch_bounds__(256) void k4b_final(
    const float* __restrict__ stage, const float2* __restrict__ params,
    float* __restrict__ out)
{
  __shared__ float tile[64][65];
  int blk = blockIdx.x;
  int b = blk >> 6, n0 = (blk & 63) * 64;
  int t = threadIdx.x;
  int o = t & 63;
  float2 pr = params[b*64 + o];
  for (int i = t; i < 4096; i += 256) {
    int nn = i >> 6;
    float y = (stage[((size_t)b*4096 + n0 + nn)*64 + o] - pr.x) * pr.y;
    tile[nn][o] = (y >= 0.f) ? y : 0.2f * y;
  }
  __syncthreads();
  for (int i = t; i < 4096; i += 256) {
    int oo = i >> 6, nn = i & 63;
    out[((size_t)(b*64 + oo))*4096 + n0 + nn] = tile[nn][oo];
  }
}

// ---------------------------------------------------------------------------
extern "C" void kernel_launch(void* const* d_in, const int* in_sizes, int n_in,
                              void* d_out, int out_size, void* d_ws, size_t ws_size,
                              hipStream_t stream)
{
  (void)in_sizes; (void)n_in; (void)out_size; (void)ws_size;
  const float* x = (const float*)d_in[0];   // (4,64,4096)
  const float* W = (const float*)d_in[1];   // (64,128)
  float* out = (float*)d_out;

  char* ws = (char*)d_ws;
  size_t off = 0;
  auto alloc = [&](size_t bytes) {
    char* p = ws + off;
    off = (off + bytes + 255) & ~(size_t)255;
    return p;
  };
  float*          uT       = (float*)         alloc((size_t)NROW*64*4);
  float*          vT       = (float*)         alloc((size_t)NROW*64*4);
  float*          xT       = (float*)         alloc((size_t)NROW*64*4);
  float*          stage    = (float*)         alloc((size_t)NROW*64*4);
  unsigned short* xh2      = (unsigned short*)alloc((size_t)NROW*80*2);
  double*         xxd      = (double*)        alloc((size_t)NROW*8);
  float*          Trow     = (float*)         alloc((size_t)NROW*4);
  double*         pS1      = (double*)        alloc((size_t)NROW*64*8);
  double*         pS2      = (double*)        alloc((size_t)NROW*64*8);
  double*         part1    = (double*)        alloc((size_t)256*64*8);
  double*         part2    = (double*)        alloc((size_t)256*64*8);
  unsigned*       bitmap   = (unsigned*)      alloc((size_t)NROW*128*4);
  float2*         params   = (float2*)        alloc(256*8);

  k1_prep    <<<256,  256, 0, stream>>>(x, W, xT, xh2, xxd, Trow, uT, vT);
  k2_screen  <<<1024, 256, 0, stream>>>(xh2, Trow, bitmap);
  k3_select  <<<4096, 256, 0, stream>>>(xT, xxd, Trow, bitmap, uT, vT,
                                        stage, pS1, pS2);
  k4a1_reduce<<<256,  256, 0, stream>>>(pS1, pS2, part1, part2);
  k4a2_params<<<4,    256, 0, stream>>>(part1, part2, params);
  k4b_final  <<<256,  256, 0, stream>>>(stage, params, out);
}

// Round 20
// 136.141 us; speedup vs baseline: 1.6674x; 1.6417x over previous
//
#include <hip/hip_runtime.h>
#include <hip/hip_bf16.h>
#include <cstdint>
#include <cstddef>

// Problem constants (fixed by reference)
#define BB 4
#define NN 4096
#define NROW (BB*NN)          // 16384 rows
#define CAP3 512              // max survivors handled by k3 (8 sort rounds)
#define ZWH 2.05f             // Wilson-Hilferty quantile z for noncentral chi2:
                              // T_d = f*(1-c-z*sqrt(c))^3, f=64+xx, c=(2/9)(64+2xx)/f^2
                              // ANCHORED: matches global T=27 (r2-r8, lambda~100, 0 undercounts)
#define SLACK 0.40            // guard slack: > E = 0.31 (fp16 screen + xx-in-K)

typedef float v2f   __attribute__((ext_vector_type(2)));
typedef float f32x16 __attribute__((ext_vector_type(16)));
typedef short s16x8 __attribute__((ext_vector_type(8)));
typedef _Float16 f16x8 __attribute__((ext_vector_type(8)));

__device__ __forceinline__ v2f pkfma(v2f a, v2f b, v2f c) {
  return __builtin_elementwise_fma(a, b, c);
}

// 64-lane bitonic sort (ascending), full network
__device__ __forceinline__ unsigned long long sort64(unsigned long long S, int lane) {
  #pragma unroll
  for (int kk = 2; kk <= 64; kk <<= 1) {
    #pragma unroll
    for (int j = kk >> 1; j > 0; j >>= 1) {
      unsigned long long o = __shfl_xor(S, j);
      bool up    = ((lane & kk) == 0);
      bool lower = ((lane & j) == 0);
      unsigned long long mn = (S < o) ? S : o;
      unsigned long long mx = (S < o) ? o : S;
      S = (lower == up) ? mn : mx;
    }
  }
  return S;
}
// given L sorted asc and S sorted asc (across lanes), return lowest 64 sorted asc
__device__ __forceinline__ unsigned long long merge_low64(
    unsigned long long L, unsigned long long S, int lane) {
  unsigned long long Sr = __shfl(S, 63 - lane);
  unsigned long long lo = (L < Sr) ? L : Sr;
  #pragma unroll
  for (int j = 32; j > 0; j >>= 1) {
    unsigned long long o = __shfl_xor(lo, j);
    unsigned long long mn = (lo < o) ? lo : o;
    unsigned long long mx = (lo < o) ? o : lo;
    lo = ((lane & j) == 0) ? mn : mx;
  }
  return lo;
}

// ---------------------------------------------------------------------------
// K1: prep. xT f32 [point][c]; xh2 fp16 [point][80] (64 dims + xx at 64 + 0s);
// xxd f64 norms; Trow (WH noncentral-chi2 quantile); uT = W1.x, vT = (W2-W1).x
// ---------------------------------------------------------------------------
__global__ __launch_bounds__(256) void k1_prep(
    const float* __restrict__ x, const float* __restrict__ W,
    float* __restrict__ xT, unsigned short* __restrict__ xh2,
    double* __restrict__ xxd, float* __restrict__ Trow,
    float* __restrict__ uT, float* __restrict__ vT)
{
  __shared__ float xc[64][65];   // [c][n]
  __shared__ float xr[64][68];   // [n][c]
  __shared__ float w1[64][65];
  __shared__ float wd[64][65];
  int t = threadIdx.x;
  int b  = blockIdx.x >> 6;
  int n0 = (blockIdx.x & 63) * 64;

  for (int i = t; i < 4096; i += 256) {
    int o = i >> 6, c = i & 63;
    float a = W[o*128 + c];
    w1[o][c] = a;
    wd[o][c] = W[o*128 + 64 + c] - a;
  }
  for (int i = t; i < 4096; i += 256) {
    int c = i >> 6, n = i & 63;
    xc[c][n] = x[((size_t)b*64 + c)*4096 + n0 + n];
  }
  __syncthreads();

  for (int i = t; i < 4096; i += 256) {
    int n = i >> 6, c = i & 63;
    float v = xc[c][n];
    xr[n][c] = v;
    size_t pt = (size_t)b*4096 + n0 + n;
    xT[pt*64 + c] = v;
    xh2[pt*80 + c] = __builtin_bit_cast(unsigned short, (_Float16)v);  // RNE
  }
  if (t < 64) {
    int n = t;
    float s0=0,s1=0,s2=0,s3=0; double sd=0.0;
    for (int c = 0; c < 64; c += 4) {
      float a0=xc[c][n],a1=xc[c+1][n],a2=xc[c+2][n],a3=xc[c+3][n];
      s0=fmaf(a0,a0,s0); s1=fmaf(a1,a1,s1); s2=fmaf(a2,a2,s2); s3=fmaf(a3,a3,s3);
      sd += (double)a0*a0 + (double)a1*a1 + (double)a2*a2 + (double)a3*a3;
    }
    float xxv = (s0+s1)+(s2+s3);
    size_t ri = (size_t)b*4096 + n0 + n;
    xxd[ri] = sd;
    // Wilson-Hilferty quantile of noncentral chi2_64(delta=xx): d = f*(1-c-z*sqrt(c))^3
    {
      float f  = 64.0f + xxv;
      float gq = 64.0f + 2.0f*xxv;
      float cc = (2.0f/9.0f) * gq / (f*f);
      float tmp = 1.0f - cc - ZWH*sqrtf(cc);
      Trow[ri] = f * tmp*tmp*tmp - xxv;
    }
    size_t xb2 = ri*80 + 64;
    xh2[xb2] = __builtin_bit_cast(unsigned short, (_Float16)xxv);
    #pragma unroll
    for (int q = 1; q < 16; ++q) xh2[xb2 + q] = 0;
  }
  v2f w1r[32], wdr[32];
  int o = t & 63;
  #pragma unroll
  for (int j = 0; j < 32; ++j) {
    w1r[j].x = w1[o][2*j]; w1r[j].y = w1[o][2*j+1];
    wdr[j].x = wd[o][2*j]; wdr[j].y = wd[o][2*j+1];
  }
  __syncthreads();

  for (int i = t; i < 4096; i += 256) {
    int n = i >> 6;
    v2f au; au.x=0.f; au.y=0.f;
    v2f av; av.x=0.f; av.y=0.f;
    #pragma unroll
    for (int cb = 0; cb < 16; ++cb) {
      float4 xv = *(const float4*)&xr[n][cb*4];
      v2f p0; p0.x = xv.x; p0.y = xv.y;
      v2f p1; p1.x = xv.z; p1.y = xv.w;
      au = pkfma(w1r[2*cb],   p0, au);
      au = pkfma(w1r[2*cb+1], p1, au);
      av = pkfma(wdr[2*cb],   p0, av);
      av = pkfma(wdr[2*cb+1], p1, av);
    }
    size_t idx = ((size_t)b*4096 + n0 + n)*64 + o;
    uT[idx] = au.x + au.y;
    vT[idx] = av.x + av.y;
  }
}

// ---------------------------------------------------------------------------
// K2: fp16 MFMA Gram screen -> survivor BITMAP. Inverted orientation:
// A = m-points (rows), B = n-points (cols, lane-owned). Screen value baked
// into K-dim 64 (A: xx_m, B: -0.5) so compare is S' > -T_n/2 (per-lane reg).
// ---------------------------------------------------------------------------
__global__ __launch_bounds__(256) void k2_screen(
    const unsigned short* __restrict__ xh2, const float* __restrict__ Trow,
    unsigned* __restrict__ bitmap)
{
  int t  = threadIdx.x;
  int nblk = blockIdx.x >> 3;
  int ms   = blockIdx.x & 7;
  int row0 = nblk * 128;
  int b = row0 >> 12;
  int wv = t >> 6, lane = t & 63;
  int lr = lane & 31, oct = lane >> 5;
  int n = row0 + wv*32 + lr;             // lane-owned output row

  s16x8 bn[5];
  #pragma unroll
  for (int ks = 0; ks < 4; ++ks)
    bn[ks] = *(const s16x8*)(xh2 + (size_t)n*80 + ks*16 + oct*8);
  {
    s16x8 z;
    #pragma unroll
    for (int q = 0; q < 8; ++q) z[q] = 0;
    if (!oct) z[0] = (short)0xB800;      // -0.5 in fp16
    bn[4] = z;
  }
  float cn = -0.5f * Trow[n];

  const unsigned short* xmB = xh2 + (size_t)b*4096*80;
  int mbase = ms * 512;

  for (int mt = 0; mt < 8; ++mt) {
    int m0 = mbase + mt*64;
    s16x8 am0[5], am1[5];
    #pragma unroll
    for (int ks = 0; ks < 4; ++ks) {
      am0[ks] = *(const s16x8*)(xmB + (size_t)(m0 + lr)*80      + ks*16 + oct*8);
      am1[ks] = *(const s16x8*)(xmB + (size_t)(m0 + 32 + lr)*80 + ks*16 + oct*8);
    }
    am0[4] = *(const s16x8*)(xmB + (size_t)(m0 + lr)*80      + 64 + oct*8);
    am1[4] = *(const s16x8*)(xmB + (size_t)(m0 + 32 + lr)*80 + 64 + oct*8);

    f32x16 a0, a1;
    #pragma unroll
    for (int i = 0; i < 16; ++i) { a0[i] = 0.f; a1[i] = 0.f; }
    #pragma unroll
    for (int ks = 0; ks < 5; ++ks) {
      f16x8 B = __builtin_bit_cast(f16x8, bn[ks]);
      a0 = __builtin_amdgcn_mfma_f32_32x32x16_f16(
             __builtin_bit_cast(f16x8, am0[ks]), B, a0, 0, 0, 0);
      a1 = __builtin_amdgcn_mfma_f32_32x32x16_f16(
             __builtin_bit_cast(f16x8, am1[ks]), B, a1, 0, 0, 0);
    }

    unsigned ua[4] = {0u,0u,0u,0u}, ub[4] = {0u,0u,0u,0u};
    #pragma unroll
    for (int i = 0; i < 16; ++i) {
      int p = (i & 3) + 8*(i >> 2) + 4*oct;   // C/D row map (measured)
      unsigned bit = 1u << p;
      ua[i & 3] = (a0[i] > cn) ? (ua[i & 3] | bit) : ua[i & 3];
      ub[i & 3] = (a1[i] > cn) ? (ub[i & 3] | bit) : ub[i & 3];
    }
    unsigned u0 = (ua[0] | ua[1]) | (ua[2] | ua[3]);
    unsigned u1 = (ub[0] | ub[1]) | (ub[2] | ub[3]);
    unsigned w0 = u0 | (unsigned)__shfl_xor((int)u0, 32);
    unsigned w1 = u1 | (unsigned)__shfl_xor((int)u1, 32);
    bitmap[(size_t)n*128 + ms*16 + mt*2 + oct] = oct ? w1 : w0;
  }
}

// ---------------------------------------------------------------------------
// K3: per-row wave. Bitmap -> compact (<=512); <=8 rounds f64 rescore +
// sort64 + merge_low64; guard d20-xxn < Trow-SLACK proves exactness;
// gather/max epilogue.
// ---------------------------------------------------------------------------
__global__ __launch_bounds__(256) void k3_select(
    const float* __restrict__ xT, const double* __restrict__ xxd,
    const float* __restrict__ Trow, const unsigned* __restrict__ bitmap,
    const float* __restrict__ uT, const float* __restrict__ vT,
    float* __restrict__ stage, double* __restrict__ pS1, double* __restrict__ pS2,
    unsigned* __restrict__ slowcnt, unsigned* __restrict__ slowlist)
{
  __shared__ unsigned short candm[4][CAP3];
  int wv = threadIdx.x >> 6, lane = threadIdx.x & 63;
  int row = blockIdx.x * 4 + wv;
  int b = row >> 12;

  double s1t = 0.0, s2t = 0.0;
  double xxn = xxd[row];

  uint2 wds = *(const uint2*)&bitmap[(size_t)row*128 + lane*2];
  int myc = __popc(wds.x) + __popc(wds.y);
  int inc = myc;
  #pragma unroll
  for (int d = 1; d < 64; d <<= 1) {
    int v = __shfl_up(inc, d);
    if (lane >= d) inc += v;
  }
  int total = __shfl(inc, 63);
  int off = inc - myc;
  bool slow = (total < 20) || (total > CAP3);

  if (!slow) {
    unsigned w = wds.x; int mb = lane*64;
    while (w) { int j = __ffs(w) - 1; w &= w - 1;
                candm[wv][off++] = (unsigned short)(mb + j); }
    w = wds.y; mb = lane*64 + 32;
    while (w) { int j = __ffs(w) - 1; w &= w - 1;
                candm[wv][off++] = (unsigned short)(mb + j); }
  }
  __builtin_amdgcn_wave_barrier();

  if (!slow) {
    const float* pn = xT + (size_t)row*64;
    int nr = (total + 63) >> 6;
    unsigned long long L = ~0ull;
    for (int r = 0; r < nr; ++r) {
      int ci = r*64 + lane;
      unsigned long long S = ~0ull;
      if (ci < total) {
        int m = (int)candm[wv][ci];
        const float* pm = xT + ((size_t)b*4096 + m)*64;
        double acc0 = 0.0, acc1 = 0.0;
        #pragma unroll
        for (int c5 = 0; c5 < 64; c5 += 4) {
          float4 A = *(const float4*)(pn + c5);
          float4 B = *(const float4*)(pm + c5);
          acc0 = fma((double)A.x, (double)B.x, acc0);
          acc1 = fma((double)A.y, (double)B.y, acc1);
          acc0 = fma((double)A.z, (double)B.z, acc0);
          acc1 = fma((double)A.w, (double)B.w, acc1);
        }
        double d = xxn + xxd[(size_t)b*4096 + m] - 2.0*(acc0 + acc1);
        d = fmax(d, 0.0);
        S = (((unsigned long long)__double_as_longlong(d)) & ~0xFFFull)
          | (unsigned long long)m;            // tie -> lower index (lax.top_k)
      }
      S = sort64(S, lane);
      L = (r == 0) ? S : merge_low64(L, S, lane);
    }
    unsigned long long k19 = __shfl(L, 19);
    double d20 = __longlong_as_double((long long)(k19 & ~0xFFFull));
    float Tr = Trow[row];
    if (!(d20 - xxn < (double)Tr - SLACK)) {
      slow = true;
    } else {
      int mlow = (int)(L & 0xFFFull);          // lanes 0..19 = top-20
      const float* ub = uT + (size_t)b*4096*64;
      float mx = -3.4e38f, s1 = 0.f, s2 = 0.f;
      #pragma unroll
      for (int k = 0; k < 20; ++k) {
        int m = __shfl(mlow, k);
        float g = ub[(size_t)m*64 + lane];
        mx = fmaxf(mx, g); s1 += g; s2 = fmaf(g, g, s2);
      }
      size_t ro = (size_t)row*64 + lane;
      float v = vT[ro];
      stage[ro] = mx + v;
      double dv = (double)v;
      s1t = (double)s1 + 20.0*dv;
      s2t = (double)s2 + 2.0*dv*(double)s1 + 20.0*dv*dv;
    }
  }
  if (slow && lane == 0) {
    unsigned i = atomicAdd(slowcnt, 1u); slowlist[i] = row;
  }
  pS1[(size_t)row*64 + lane] = s1t;   // zeros for slow rows (k3b adds theirs)
  pS2[(size_t)row*64 + lane] = s2t;
}

// ---------------------------------------------------------------------------
// K3b: safety slow path (expected ~0 rows with WH threshold). Sort-on-demand:
// round 0 sorts 64 keys -> kth; later rounds compact keys < kth into pending
// buffer; sort64+merge only on overflow. Cross-wave merge at the end.
// ---------------------------------------------------------------------------
__global__ __launch_bounds__(256) void k3b_slow(
    const float* __restrict__ xT, const double* __restrict__ xxd,
    const unsigned* __restrict__ slowcnt, const unsigned* __restrict__ slowlist,
    const float* __restrict__ uT, const float* __restrict__ vT,
    float* __restrict__ stage, double* __restrict__ k3bS1, double* __restrict__ k3bS2)
{
  __shared__ unsigned long long wtop[4][64];
  __shared__ unsigned long long pend[4][64];
  __shared__ unsigned t20[20];
  unsigned nslow = *slowcnt;
  int t = threadIdx.x, wv = t >> 6, lane = t & 63;
  for (unsigned ii = blockIdx.x; ii < nslow; ii += gridDim.x) {
    int row = (int)slowlist[ii];
    int b = row >> 12, n = row & 4095;
    const float* pn = xT + ((size_t)b*4096 + n)*64;
    double xxn = xxd[(size_t)b*4096 + n];

    unsigned long long L;
    unsigned long long kth;
    int pc = 0;
    for (int r = 0; r < 16; ++r) {
      int m = wv*1024 + r*64 + lane;
      const float* pm = xT + ((size_t)b*4096 + m)*64;
      double acc0 = 0.0, acc1 = 0.0;
      #pragma unroll
      for (int c5 = 0; c5 < 64; c5 += 4) {
        float4 A = *(const float4*)(pn + c5);
        float4 B = *(const float4*)(pm + c5);
        acc0 = fma((double)A.x, (double)B.x, acc0);
        acc1 = fma((double)A.y, (double)B.y, acc1);
        acc0 = fma((double)A.z, (double)B.z, acc0);
        acc1 = fma((double)A.w, (double)B.w, acc1);
      }
      double d = xxn + xxd[(size_t)b*4096 + m] - 2.0*(acc0 + acc1);
      d = fmax(d, 0.0);
      unsigned long long S =
          (((unsigned long long)__double_as_longlong(d)) & ~0xFFFull)
        | (unsigned long long)m;              // tie -> lower index
      if (r == 0) {
        L = sort64(S, lane);
        kth = __shfl(L, 63);
        continue;
      }
      bool take = (S < kth);
      unsigned long long mk = __ballot(take);
      int cnt = __popcll(mk);
      if (pc + cnt > 64) {                    // flush pending
        __builtin_amdgcn_wave_barrier();
        unsigned long long P = (lane < pc) ? pend[wv][lane] : ~0ull;
        P = sort64(P, lane);
        L = merge_low64(L, P, lane);
        kth = __shfl(L, 63);
        pc = 0;
      }
      if (take) {
        int pos = pc + __popcll(mk & ((1ull << lane) - 1ull));
        pend[wv][pos] = S;
      }
      pc += cnt;
      __builtin_amdgcn_wave_barrier();
    }
    if (pc > 0) {                             // final flush
      __builtin_amdgcn_wave_barrier();
      unsigned long long P = (lane < pc) ? pend[wv][lane] : ~0ull;
      P = sort64(P, lane);
      L = merge_low64(L, P, lane);
    }
    wtop[wv][lane] = L;
    __syncthreads();
    if (wv == 0) {
      unsigned long long m01 = merge_low64(wtop[0][lane],
                                           wtop[1][lane], lane);
      unsigned long long m23 = merge_low64(wtop[2][lane],
                                           wtop[3][lane], lane);
      unsigned long long F = merge_low64(m01, m23, lane);
      if (lane < 20) t20[lane] = (unsigned)(F & 0xFFFull);
    }
    __syncthreads();
    if (t < 64) {
      const float* ub = uT + (size_t)b*4096*64;
      float mx = -3.4e38f, s1 = 0.f, s2 = 0.f;
      #pragma unroll
      for (int k = 0; k < 20; ++k) {
        unsigned m = t20[k];
        float g = ub[(size_t)m*64 + t];
        mx = fmaxf(mx, g); s1 += g; s2 = fmaf(g, g, s2);
      }
      size_t ro = ((size_t)b*4096 + n)*64 + t;
      float v = vT[ro];
      stage[ro] = mx + v;
      double dv = (double)v;
      __hip_atomic_fetch_add(&k3bS1[b*64 + t], (double)s1 + 20.0*dv,
                             __ATOMIC_RELAXED, __HIP_MEMORY_SCOPE_AGENT);
      __hip_atomic_fetch_add(&k3bS2[b*64 + t], (double)s2 + 2.0*dv*(double)s1 + 20.0*dv*dv,
                             __ATOMIC_RELAXED, __HIP_MEMORY_SCOPE_AGENT);
    }
    __syncthreads();
  }
}

// ---------------------------------------------------------------------------
// K4a1: stage-1 reduction. 256 blocks; block reduces 64 rows -> part[blk][o].
// ---------------------------------------------------------------------------
__global__ __launch_bounds__(256) void k4a1_reduce(
    const double* __restrict__ pS1, const double* __restrict__ pS2,
    double* __restrict__ part1, double* __restrict__ part2)
{
  __shared__ double r1[4][64], r2[4][64];
  int blk = blockIdx.x;                 // rows blk*64 .. blk*64+63
  int t = threadIdx.x, wv = t >> 6, o = t & 63;
  size_t rbase = (size_t)blk*64 + wv*16;
  double s1 = 0.0, s2 = 0.0;
  for (int j = 0; j < 16; ++j) {
    s1 += pS1[(rbase + j)*64 + o];
    s2 += pS2[(rbase + j)*64 + o];
  }
  r1[wv][o] = s1; r2[wv][o] = s2;
  __syncthreads();
  if (wv == 0) {
    part1[(size_t)blk*64 + o] = r1[0][o]+r1[1][o]+r1[2][o]+r1[3][o];
    part2[(size_t)blk*64 + o] = r2[0][o]+r2[1][o]+r2[2][o]+r2[3][o];
  }
}

// ---------------------------------------------------------------------------
// K4a2: stage-2. 4 blocks; reduce 64 chunk-partials per (b,o) + k3b -> params.
// ---------------------------------------------------------------------------
__global__ __launch_bounds__(256) void k4a2_params(
    const double* __restrict__ part1, const double* __restrict__ part2,
    const double* __restrict__ k3bS1, const double* __restrict__ k3bS2,
    float2* __restrict__ params)
{
  __shared__ double r1[4][64], r2[4][64];
  int b = blockIdx.x;
  int t = threadIdx.x, wv = t >> 6, o = t & 63;
  double s1 = 0.0, s2 = 0.0;
  for (int j = wv*16; j < wv*16 + 16; ++j) {
    s1 += part1[((size_t)b*64 + j)*64 + o];
    s2 += part2[((size_t)b*64 + j)*64 + o];
  }
  r1[wv][o] = s1; r2[wv][o] = s2;
  __syncthreads();
  if (wv == 0) {
    double S1 = k3bS1[b*64 + o] + r1[0][o]+r1[1][o]+r1[2][o]+r1[3][o];
    double S2 = k3bS2[b*64 + o] + r2[0][o]+r2[1][o]+r2[2][o]+r2[3][o];
    double inv = 1.0 / (4096.0 * 20.0);
    double mean = S1 * inv;
    double var  = S2 * inv - mean * mean;
    float2 pr; pr.x = (float)mean; pr.y = (float)rsqrt(var + 1e-5);
    params[b*64 + o] = pr;
  }
}

// ---------------------------------------------------------------------------
// K4b: normalize + leaky-ReLU + transpose [point][o] -> [b][o][n] via LDS.
// ---------------------------------------------------------------------------
__global__ __launch_bounds__(256) void k4b_final(
    const float* __restrict__ stage, const float2* __restrict__ params,
    float* __restrict__ out)
{
  __shared__ float tile[64][65];
  int blk = blockIdx.x;
  int b = blk >> 6, n0 = (blk & 63) * 64;
  int t = threadIdx.x;
  int o = t & 63;
  float2 pr = params[b*64 + o];
  for (int i = t; i < 4096; i += 256) {
    int nn = i >> 6;
    float y = (stage[((size_t)b*4096 + n0 + nn)*64 + o] - pr.x) * pr.y;
    tile[nn][o] = (y >= 0.f) ? y : 0.2f * y;
  }
  __syncthreads();
  for (int i = t; i < 4096; i += 256) {
    int oo = i >> 6, nn = i & 63;
    out[((size_t)(b*64 + oo))*4096 + n0 + nn] = tile[nn][oo];
  }
}

// ---------------------------------------------------------------------------
extern "C" void kernel_launch(void* const* d_in, const int* in_sizes, int n_in,
                              void* d_out, int out_size, void* d_ws, size_t ws_size,
                              hipStream_t stream)
{
  (void)in_sizes; (void)n_in; (void)out_size; (void)ws_size;
  const float* x = (const float*)d_in[0];   // (4,64,4096)
  const float* W = (const float*)d_in[1];   // (64,128)
  float* out = (float*)d_out;

  char* ws = (char*)d_ws;
  size_t off = 0;
  auto alloc = [&](size_t bytes) {
    char* p = ws + off;
    off = (off + bytes + 255) & ~(size_t)255;
    return p;
  };
  float*          uT       = (float*)         alloc((size_t)NROW*64*4);
  float*          vT       = (float*)         alloc((size_t)NROW*64*4);
  float*          xT       = (float*)         alloc((size_t)NROW*64*4);
  float*          stage    = (float*)         alloc((size_t)NROW*64*4);
  unsigned short* xh2      = (unsigned short*)alloc((size_t)NROW*80*2);
  double*         xxd      = (double*)        alloc((size_t)NROW*8);
  float*          Trow     = (float*)         alloc((size_t)NROW*4);
  double*         pS1      = (double*)        alloc((size_t)NROW*64*8);
  double*         pS2      = (double*)        alloc((size_t)NROW*64*8);
  double*         part1    = (double*)        alloc((size_t)256*64*8);
  double*         part2    = (double*)        alloc((size_t)256*64*8);
  unsigned*       bitmap   = (unsigned*)      alloc((size_t)NROW*128*4);
  float2*         params   = (float2*)        alloc(256*8);
  // zeroed region (contiguous): slowcnt, k3bS1, k3bS2
  unsigned*       slowcnt  = (unsigned*)      alloc(256);
  double*         k3bS1    = (double*)        alloc(256*8);
  double*         k3bS2    = (double*)        alloc(256*8);
  unsigned*       slowlist = (unsigned*)      alloc((size_t)NROW*4);

  hipMemsetAsync(slowcnt, 0, 256 + 2048 + 2048, stream);

  k1_prep    <<<256,  256, 0, stream>>>(x, W, xT, xh2, xxd, Trow, uT, vT);
  k2_screen  <<<1024, 256, 0, stream>>>(xh2, Trow, bitmap);
  k3_select  <<<4096, 256, 0, stream>>>(xT, xxd, Trow, bitmap, uT, vT,
                                        stage, pS1, pS2, slowcnt, slowlist);
  k3b_slow   <<<512,  256, 0, stream>>>(xT, xxd, slowcnt, slowlist,
                                        uT, vT, stage, k3bS1, k3bS2);
  k4a1_reduce<<<256,  256, 0, stream>>>(pS1, pS2, part1, part2);
  k4a2_params<<<4,    256, 0, stream>>>(part1, part2, k3bS1, k3bS2, params);
  k4b_final  <<<256,  256, 0, stream>>>(stage, params, out);
}